// Round 9
// baseline (363.093 us; speedup 1.0000x reference)
//
#include <hip/hip_runtime.h>
#include <math.h>

// ---------- types ----------
typedef __attribute__((ext_vector_type(8))) short short8;
typedef __attribute__((ext_vector_type(8))) _Float16 half8;
typedef __attribute__((ext_vector_type(2))) __fp16 fp16x2;
typedef __attribute__((ext_vector_type(4))) float float4v;
typedef __attribute__((ext_vector_type(4))) unsigned short ushort4v;

__device__ __forceinline__ unsigned short f2bf(float f) {
  union { unsigned int i; float f; } x; x.f = f;
  unsigned int r = x.i + 0x7fffu + ((x.i >> 16) & 1u);  // round-nearest-even
  return (unsigned short)(r >> 16);
}

// branch-free exact-GELU via Abramowitz-Stegun 7.1.26 (|erf err| <= 1.5e-7)
__device__ __forceinline__ float gelu_f(float y) {
  const float z = fabsf(y) * 0.70710678118654752f;
  const float t = 1.0f / (1.0f + 0.3275911f * z);
  const float poly = t * (0.254829592f + t * (-0.284496736f +
                     t * (1.421413741f + t * (-1.453152027f + t * 1.061405429f))));
  const float e = exp2f(-z * z * 1.44269504088896f);
  const float erfz = copysignf(1.0f - poly * e, y);
  return 0.5f * y * (1.0f + erfz);
}

// ---------- LayerNorm row body (one row per wave) ----------
__device__ __forceinline__ void ln_row(const float* __restrict__ in,
                                       const float* __restrict__ g,
                                       const float* __restrict__ b,
                                       unsigned short* __restrict__ out,
                                       int row, int lane) {
  const float* xr = in + (size_t)row * 768 + lane * 4;
  const float4 v0 = *(const float4*)(xr);
  const float4 v1 = *(const float4*)(xr + 256);
  const float4 v2 = *(const float4*)(xr + 512);
  float s  = (v0.x + v0.y) + (v0.z + v0.w) + (v1.x + v1.y) + (v1.z + v1.w)
           + (v2.x + v2.y) + (v2.z + v2.w);
  float s2 = v0.x*v0.x + v0.y*v0.y + v0.z*v0.z + v0.w*v0.w
           + v1.x*v1.x + v1.y*v1.y + v1.z*v1.z + v1.w*v1.w
           + v2.x*v2.x + v2.y*v2.y + v2.z*v2.z + v2.w*v2.w;
  for (int off = 32; off > 0; off >>= 1) {
    s  += __shfl_xor(s, off, 64);
    s2 += __shfl_xor(s2, off, 64);
  }
  const float mu = s * (1.0f / 768.0f);
  const float var = s2 * (1.0f / 768.0f) - mu * mu;
  const float rstd = rsqrtf(var + 1e-5f);
  const float* gp = g + lane * 4;
  const float* bp = b + lane * 4;
  unsigned short* orow = out + (size_t)row * 768 + lane * 4;
#pragma unroll
  for (int k = 0; k < 3; ++k) {
    const float4 v = (k == 0) ? v0 : (k == 1) ? v1 : v2;
    const float4 gv = *(const float4*)(gp + k * 256);
    const float4 bv = *(const float4*)(bp + k * 256);
    ushort4v o;
    o.x = f2bf((v.x - mu) * rstd * gv.x + bv.x);
    o.y = f2bf((v.y - mu) * rstd * gv.y + bv.y);
    o.z = f2bf((v.z - mu) * rstd * gv.z + bv.z);
    o.w = f2bf((v.w - mu) * rstd * gv.w + bv.w);
    *(ushort4v*)(orow + k * 256) = o;
  }
}

// ---------- LayerNorm kernel ----------
__global__ void ln_kernel(const float* __restrict__ in, const float* __restrict__ g,
                          const float* __restrict__ b, unsigned short* __restrict__ out) {
  ln_row(in, g, b, out, blockIdx.x * 4 + (threadIdx.x >> 6), threadIdx.x & 63);
}

// ---------- wtrans body: f32 (K,N) -> bf16 (N,K), one 32x32 tile ----------
__device__ __forceinline__ void wtrans_tile(const float* __restrict__ in,
                                            unsigned short* __restrict__ out,
                                            int K, int N, int bx, int by) {
  __shared__ float tile[32][33];
  const int k0 = by * 32, n0 = bx * 32;
  const int tr = threadIdx.x >> 5, tc = threadIdx.x & 31;
#pragma unroll
  for (int i = 0; i < 4; ++i)
    tile[tr + i * 8][tc] = in[(size_t)(k0 + tr + i * 8) * N + n0 + tc];
  __syncthreads();
#pragma unroll
  for (int i = 0; i < 4; ++i)
    out[(size_t)(n0 + tr + i * 8) * K + k0 + tc] = f2bf(tile[tc][tr + i * 8]);
}

// ---------- fused: ln1 (2048 blocks) + w_kv trans (1152) + w_out trans (576) ----------
// Branch is block-uniform (blockIdx-based) -> __syncthreads inside is safe.
__global__ void prep1_kernel(const float* __restrict__ x, const float* __restrict__ g,
                             const float* __restrict__ b, unsigned short* __restrict__ xn,
                             const float* __restrict__ wkv, unsigned short* __restrict__ wkvt,
                             const float* __restrict__ wout, unsigned short* __restrict__ woutt) {
  int id = (int)blockIdx.x;
  if (id < 2048) {
    ln_row(x, g, b, xn, id * 4 + (threadIdx.x >> 6), threadIdx.x & 63);
  } else if (id < 2048 + 1152) {
    id -= 2048;
    wtrans_tile(wkv, wkvt, 768, 1536, id % 48, id / 48);
  } else {
    id -= 2048 + 1152;
    wtrans_tile(wout, woutt, 768, 768, id % 24, id / 24);
  }
}

// ---------- fused pair of weight transposes (w1 + w2) ----------
__global__ void wtrans2_kernel(const float* __restrict__ inA, unsigned short* __restrict__ outA,
                               int KA, int NA, int bxA, int nA,
                               const float* __restrict__ inB, unsigned short* __restrict__ outB,
                               int KB, int NB, int bxB) {
  int id = (int)blockIdx.x;
  if (id < nA) wtrans_tile(inA, outA, KA, NA, id % bxA, id / bxA);
  else { id -= nA; wtrans_tile(inB, outB, KB, NB, id % bxB, id / bxB); }
}

// ---------- XCD-aware block swizzle ----------
#define SWIZ_BLOCK(GX, TW)                                        \
  const int _id = (int)blockIdx.x;                                \
  const int _gy8 = (int)gridDim.x / (8 * (GX));                   \
  const int _xcd = _id & 7, _jj = _id >> 3;                       \
  const int row0 = (_xcd * _gy8 + _jj / (GX)) * 128;              \
  const int col0 = (_jj % (GX)) * (TW);

#define ASM_FENCE asm volatile("" ::: "memory")

// ---------- GEMM core 128x128, BK=64, XOR-swizzled LDS (single-buffer) ----------
// Proven best for >=5-blocks/CU kernels (cross-block TLP hides the drain).
__device__ __forceinline__ void gemm128(
    const unsigned short* __restrict__ A, int lda,
    const unsigned short* __restrict__ Bt, int ldb, int K,
    int row0, int col0,
    unsigned short* As, unsigned short* Bs,
    float4v acc[4][4]) {
  const int t = threadIdx.x, lane = t & 63, wave = t >> 6;
  const int quad = lane >> 4, l16 = lane & 15;
  const int wr = wave >> 1, wc = wave & 1;
  const int srow = lane >> 3;
  const int scol = ((lane & 7) ^ srow) * 8;
#pragma unroll
  for (int mt = 0; mt < 4; ++mt)
#pragma unroll
    for (int nt = 0; nt < 4; ++nt) acc[mt][nt] = (float4v)(0.0f);

  for (int kk = 0; kk < K; kk += 64) {
    __syncthreads();
#pragma unroll
    for (int j = 0; j < 4; ++j) {
      const int chunk = wave * 4 + j;
      const int r = chunk * 8 + srow;
      __builtin_amdgcn_global_load_lds(
          (const __attribute__((address_space(1))) unsigned int*)(A + (size_t)(row0 + r) * lda + kk + scol),
          (__attribute__((address_space(3))) unsigned int*)(As + chunk * 512),
          16, 0, 0);
      __builtin_amdgcn_global_load_lds(
          (const __attribute__((address_space(1))) unsigned int*)(Bt + (size_t)(col0 + r) * ldb + kk + scol),
          (__attribute__((address_space(3))) unsigned int*)(Bs + chunk * 512),
          16, 0, 0);
    }
    __syncthreads();
#pragma unroll
    for (int ks = 0; ks < 2; ++ks) {
      const int gsw = ((ks * 4 + quad) ^ (l16 & 7)) * 8;
      short8 af[4], bfv[4];
#pragma unroll
      for (int i = 0; i < 4; ++i) {
        af[i]  = *(const short8*)(As + (wr * 64 + i * 16 + l16) * 64 + gsw);
        bfv[i] = *(const short8*)(Bs + (wc * 64 + i * 16 + l16) * 64 + gsw);
      }
#pragma unroll
      for (int mt = 0; mt < 4; ++mt)
#pragma unroll
        for (int nt = 0; nt < 4; ++nt)
          acc[mt][nt] = __builtin_amdgcn_mfma_f32_16x16x32_bf16(af[mt], bfv[nt], acc[mt][nt], 0, 0, 0);
    }
  }
}

#define GEMM128_PROLOGUE(GX)                                     \
  __shared__ unsigned short As[128 * 64];                        \
  __shared__ unsigned short Bs[128 * 64];                        \
  float4v acc[4][4];                                             \
  SWIZ_BLOCK(GX, 128)                                            \
  const int t = threadIdx.x, lane = t & 63, wave = t >> 6;       \
  const int quad = lane >> 4, l16 = lane & 15;                   \
  const int wr = wave >> 1, wc = wave & 1; (void)t;

// ---------- GEMM core 128x64, BK=64, counted-vmcnt double-buffer ----------
// Proven win for 3-blocks/CU-resident kernels (outproj, mlp2, now kv).
__device__ __forceinline__ void stage12864(
    const unsigned short* __restrict__ A, int lda,
    const unsigned short* __restrict__ Bt, int ldb,
    int row0, int col0, int kk,
    unsigned short* Asb, unsigned short* Bsb,
    int wave, int srow, int scol) {
#pragma unroll
  for (int j = 0; j < 4; ++j) {
    const int chunk = wave * 4 + j;
    const int r = chunk * 8 + srow;
    __builtin_amdgcn_global_load_lds(
        (const __attribute__((address_space(1))) unsigned int*)(A + (size_t)(row0 + r) * lda + kk + scol),
        (__attribute__((address_space(3))) unsigned int*)(Asb + chunk * 512),
        16, 0, 0);
  }
#pragma unroll
  for (int j = 0; j < 2; ++j) {
    const int chunk = wave * 2 + j;
    const int r = chunk * 8 + srow;
    __builtin_amdgcn_global_load_lds(
        (const __attribute__((address_space(1))) unsigned int*)(Bt + (size_t)(col0 + r) * ldb + kk + scol),
        (__attribute__((address_space(3))) unsigned int*)(Bsb + chunk * 512),
        16, 0, 0);
  }
}

__device__ __forceinline__ void mfma_step12864(
    const unsigned short* Ab, const unsigned short* Bb,
    int wave, int quad, int l16, float4v acc[2][4]) {
#pragma unroll
  for (int ks = 0; ks < 2; ++ks) {
    const int gsw = ((ks * 4 + quad) ^ (l16 & 7)) * 8;
    short8 af[2], bfv[4];
#pragma unroll
    for (int i = 0; i < 2; ++i)
      af[i] = *(const short8*)(Ab + (wave * 32 + i * 16 + l16) * 64 + gsw);
#pragma unroll
    for (int i = 0; i < 4; ++i)
      bfv[i] = *(const short8*)(Bb + (i * 16 + l16) * 64 + gsw);
#pragma unroll
    for (int mt = 0; mt < 2; ++mt)
#pragma unroll
      for (int nt = 0; nt < 4; ++nt)
        acc[mt][nt] = __builtin_amdgcn_mfma_f32_16x16x32_bf16(af[mt], bfv[nt], acc[mt][nt], 0, 0, 0);
  }
}

// K must be a multiple of 128 and >= 256.
__device__ __forceinline__ void gemm12864(
    const unsigned short* __restrict__ A, int lda,
    const unsigned short* __restrict__ Bt, int ldb, int K,
    int row0, int col0,
    unsigned short* As, unsigned short* Bs,
    float4v acc[2][4]) {
  const int t = threadIdx.x, lane = t & 63, wave = t >> 6;
  const int quad = lane >> 4, l16 = lane & 15;
  const int srow = lane >> 3;
  const int scol = ((lane & 7) ^ srow) * 8;
#pragma unroll
  for (int mt = 0; mt < 2; ++mt)
#pragma unroll
    for (int nt = 0; nt < 4; ++nt) acc[mt][nt] = (float4v)(0.0f);

  stage12864(A, lda, Bt, ldb, row0, col0, 0, As, Bs, wave, srow, scol);
  stage12864(A, lda, Bt, ldb, row0, col0, 64, As + 8192, Bs + 4096, wave, srow, scol);

  for (int kk = 0; kk < K - 128; kk += 128) {
    asm volatile("s_waitcnt vmcnt(6)" ::: "memory");
    __builtin_amdgcn_s_barrier();
    ASM_FENCE;
    mfma_step12864(As, Bs, wave, quad, l16, acc);
    ASM_FENCE;
    __builtin_amdgcn_s_barrier();
    ASM_FENCE;
    stage12864(A, lda, Bt, ldb, row0, col0, kk + 128, As, Bs, wave, srow, scol);

    asm volatile("s_waitcnt vmcnt(6)" ::: "memory");
    __builtin_amdgcn_s_barrier();
    ASM_FENCE;
    mfma_step12864(As + 8192, Bs + 4096, wave, quad, l16, acc);
    ASM_FENCE;
    __builtin_amdgcn_s_barrier();
    ASM_FENCE;
    stage12864(A, lda, Bt, ldb, row0, col0, kk + 192, As + 8192, Bs + 4096, wave, srow, scol);
  }
  asm volatile("s_waitcnt vmcnt(6)" ::: "memory");
  __builtin_amdgcn_s_barrier();
  ASM_FENCE;
  mfma_step12864(As, Bs, wave, quad, l16, acc);
  asm volatile("s_waitcnt vmcnt(0)" ::: "memory");
  __builtin_amdgcn_s_barrier();
  ASM_FENCE;
  mfma_step12864(As + 8192, Bs + 4096, wave, quad, l16, acc);
}

#define GEMM12864_PROLOGUE(GX)                                   \
  __shared__ unsigned short As[2 * 128 * 64];                    \
  __shared__ unsigned short Bs[2 * 64 * 64];                     \
  float4v acc[2][4];                                             \
  SWIZ_BLOCK(GX, 64)                                             \
  const int t = threadIdx.x, lane = t & 63, wave = t >> 6;       \
  const int quad = lane >> 4, l16 = lane & 15; (void)t;

// ---------- kv GEMM: xn @ w_kv -> k (B,H,N,DH) f16, v^T (B,H,DH,N) f16 ----------
// Round-9: 128x64 counted-vmcnt core (grid 1536 = two balanced generations of
// 3 blocks/CU) replacing the single-buffer 128^2 core at 3/CU (latency-exposed).
__global__ void gemm_kv_kernel(const unsigned short* __restrict__ xn,
                               const unsigned short* __restrict__ wkvt,
                               _Float16* __restrict__ kbuf,
                               _Float16* __restrict__ vtbuf) {
  GEMM12864_PROLOGUE(24)
  gemm12864(xn, 768, wkvt, 768, 768, row0, col0, As, Bs, acc);
#pragma unroll
  for (int mt = 0; mt < 2; ++mt)
#pragma unroll
    for (int nt = 0; nt < 4; ++nt) {
      const int j = col0 + nt * 16 + l16;
#pragma unroll
      for (int r = 0; r < 4; ++r) {
        const int m = row0 + wave * 32 + mt * 16 + quad * 4 + r;
        const int bb = m >> 10, n = m & 1023;
        const float c = acc[mt][nt][r];
        if (j < 768) {
          const int hh = j >> 6, d = j & 63;
          kbuf[((size_t)(bb * 12 + hh) * 1024 + n) * 64 + d] = (_Float16)c;
        } else {
          const int j2 = j - 768, hh = j2 >> 6, d = j2 & 63;
          vtbuf[((size_t)(bb * 12 + hh) * 64 + d) * 1024 + n] = (_Float16)c;
        }
      }
    }
}

// ---------- MFMA flash attention, f16 (qs-interleaved phases) ----------
#define AST 72
#define PST 72
__global__ __launch_bounds__(256, 3)
void attn_kernel(const float* __restrict__ q_extra,
                 const _Float16* __restrict__ kbuf,
                 const _Float16* __restrict__ vtbuf,
                 unsigned short* __restrict__ ao) {
  __shared__ _Float16 Ks[64 * AST];
  __shared__ _Float16 Vs[64 * AST];
  __shared__ _Float16 Ps[4][2][16 * PST];
  const int id = (int)blockIdx.x;
  const int pair = id % 96, qb = id / 96;
  const int h = pair >> 3, b = pair & 7;
  const int q0 = qb * 128;
  const int t = threadIdx.x, lane = t & 63, wave = t >> 6;
  const int quad = lane >> 4, l16 = lane & 15;

  // Q fragments (B-operand layout) f16, pre-scaled by 0.125*log2(e)
  const float QS = 0.125f * 1.44269504088896f;
  half8 qf[2][2];
#pragma unroll
  for (int qs = 0; qs < 2; ++qs) {
    const float* qp = q_extra +
        ((size_t)((b * 1024 + q0 + wave * 32 + qs * 16 + l16) * 12 + h)) * 64 + quad * 8;
    float4 a0 = *(const float4*)(qp);
    float4 a1 = *(const float4*)(qp + 4);
    float4 c0 = *(const float4*)(qp + 32);
    float4 c1 = *(const float4*)(qp + 36);
    union { fp16x2 h2[4]; half8 h8; } u0, u1;
    u0.h2[0] = __builtin_amdgcn_cvt_pkrtz(a0.x * QS, a0.y * QS);
    u0.h2[1] = __builtin_amdgcn_cvt_pkrtz(a0.z * QS, a0.w * QS);
    u0.h2[2] = __builtin_amdgcn_cvt_pkrtz(a1.x * QS, a1.y * QS);
    u0.h2[3] = __builtin_amdgcn_cvt_pkrtz(a1.z * QS, a1.w * QS);
    u1.h2[0] = __builtin_amdgcn_cvt_pkrtz(c0.x * QS, c0.y * QS);
    u1.h2[1] = __builtin_amdgcn_cvt_pkrtz(c0.z * QS, c0.w * QS);
    u1.h2[2] = __builtin_amdgcn_cvt_pkrtz(c1.x * QS, c1.y * QS);
    u1.h2[3] = __builtin_amdgcn_cvt_pkrtz(c1.z * QS, c1.w * QS);
    qf[qs][0] = u0.h8; qf[qs][1] = u1.h8;
  }

  const _Float16* kb = kbuf + (size_t)(b * 12 + h) * 65536;
  const _Float16* vb = vtbuf + (size_t)(b * 12 + h) * 65536;
  const int srow = t >> 2, su = (t & 3) * 16;

  // prefetch chunk 0
  half8 kp0 = *(const half8*)(kb + (size_t)srow * 64 + su);
  half8 kp1 = *(const half8*)(kb + (size_t)srow * 64 + su + 8);
  half8 vp0 = *(const half8*)(vb + (size_t)srow * 1024 + su);
  half8 vp1 = *(const half8*)(vb + (size_t)srow * 1024 + su + 8);

  float m_s[2] = {-1e30f, -1e30f}, l_s[2] = {0.0f, 0.0f};
  float4v acc[2][4];
#pragma unroll
  for (int qs = 0; qs < 2; ++qs)
#pragma unroll
    for (int nt = 0; nt < 4; ++nt) acc[qs][nt] = (float4v)(0.0f);

  for (int c = 0; c < 16; ++c) {
    __syncthreads();
    *(half8*)(Ks + srow * AST + su)     = kp0;
    *(half8*)(Ks + srow * AST + su + 8) = kp1;
    *(half8*)(Vs + srow * AST + su)     = vp0;
    *(half8*)(Vs + srow * AST + su + 8) = vp1;
    if (c < 15) {
      const int key1 = (c + 1) * 64;
      kp0 = *(const half8*)(kb + (size_t)(key1 + srow) * 64 + su);
      kp1 = *(const half8*)(kb + (size_t)(key1 + srow) * 64 + su + 8);
      vp0 = *(const half8*)(vb + (size_t)srow * 1024 + key1 + su);
      vp1 = *(const half8*)(vb + (size_t)srow * 1024 + key1 + su + 8);
    }
    __syncthreads();

    // ---- phase 1: QK^T for BOTH q-sets (32-MFMA cluster) ----
    float4v s[2][4];
    __builtin_amdgcn_s_setprio(1);
#pragma unroll
    for (int qs = 0; qs < 2; ++qs)
#pragma unroll
      for (int kt = 0; kt < 4; ++kt) {
        const _Float16* kr = Ks + (kt * 16 + l16) * AST;
        half8 kf0 = *(const half8*)(kr + quad * 8);
        half8 kf1 = *(const half8*)(kr + 32 + quad * 8);
        float4v a = (float4v)(0.f);
        a = __builtin_amdgcn_mfma_f32_16x16x32_f16(kf0, qf[qs][0], a, 0, 0, 0);
        a = __builtin_amdgcn_mfma_f32_16x16x32_f16(kf1, qf[qs][1], a, 0, 0, 0);
        s[qs][kt] = a;
      }
    __builtin_amdgcn_s_setprio(0);

    // ---- phase 2: both softmax chains (independent -> ILP) ----
#pragma unroll
    for (int qs = 0; qs < 2; ++qs) {
      const float t1 = fmaxf(fmaxf(s[qs][0][0], s[qs][0][1]), s[qs][0][2]);
      const float t2 = fmaxf(fmaxf(s[qs][0][3], s[qs][1][0]), s[qs][1][1]);
      const float t3 = fmaxf(fmaxf(s[qs][1][2], s[qs][1][3]), s[qs][2][0]);
      const float t4 = fmaxf(fmaxf(s[qs][2][1], s[qs][2][2]), s[qs][2][3]);
      const float t5 = fmaxf(fmaxf(s[qs][3][0], s[qs][3][1]), s[qs][3][2]);
      const float mx = fmaxf(fmaxf(fmaxf(t1, t2), t3),
                             fmaxf(fmaxf(t4, t5), s[qs][3][3]));

      if (__any(mx > m_s[qs] + 8.0f)) {
        float gm = fmaxf(mx, __shfl_xor(mx, 16, 64));
        gm = fmaxf(gm, __shfl_xor(gm, 32, 64));
        const float mn = fmaxf(m_s[qs], gm);
        const float alpha = exp2f(m_s[qs] - mn);
        m_s[qs] = mn;
        l_s[qs] *= alpha;
        float ab[4];
#pragma unroll
        for (int r = 0; r < 4; ++r) ab[r] = __shfl(alpha, quad * 4 + r, 64);
#pragma unroll
        for (int nt = 0; nt < 4; ++nt)
#pragma unroll
          for (int r = 0; r < 4; ++r) acc[qs][nt][r] *= ab[r];
      }

      _Float16* pw = Ps[wave][qs];
      float sum = 0.0f;
#pragma unroll
      for (int kt = 0; kt < 4; ++kt) {
        const float p0 = exp2f(s[qs][kt][0] - m_s[qs]);
        const float p1 = exp2f(s[qs][kt][1] - m_s[qs]);
        const float p2 = exp2f(s[qs][kt][2] - m_s[qs]);
        const float p3 = exp2f(s[qs][kt][3] - m_s[qs]);
        sum += (p0 + p1) + (p2 + p3);
        union { fp16x2 h2[2]; uint2 u; } pk;
        pk.h2[0] = __builtin_amdgcn_cvt_pkrtz(p0, p1);
        pk.h2[1] = __builtin_amdgcn_cvt_pkrtz(p2, p3);
        *(uint2*)(pw + l16 * PST + kt * 16 + quad * 4) = pk.u;
      }
      l_s[qs] += sum;   // per-lane partial; cross-quad reduce deferred to end
    }

    // ---- phase 3: PV for both q-sets ----
#pragma unroll
    for (int qs = 0; qs < 2; ++qs) {
      _Float16* pw = Ps[wave][qs];
      half8 pf0 = *(const half8*)(pw + l16 * PST + quad * 8);
      half8 pf1 = *(const half8*)(pw + l16 * PST + 32 + quad * 8);
      __builtin_amdgcn_s_setprio(1);
#pragma unroll
      for (int nt = 0; nt < 4; ++nt) {
        const _Float16* vr = Vs + (nt * 16 + l16) * AST;
        half8 vf0 = *(const half8*)(vr + quad * 8);
        half8 vf1 = *(const half8*)(vr + 32 + quad * 8);
        acc[qs][nt] = __builtin_amdgcn_mfma_f32_16x16x32_f16(pf0, vf0, acc[qs][nt], 0, 0, 0);
        acc[qs][nt] = __builtin_amdgcn_mfma_f32_16x16x32_f16(pf1, vf1, acc[qs][nt], 0, 0, 0);
      }
      __builtin_amdgcn_s_setprio(0);
    }
  }

#pragma unroll
  for (int qs = 0; qs < 2; ++qs) {
    // cross-quad l_s reduction (once)
    l_s[qs] += __shfl_xor(l_s[qs], 16, 64);
    l_s[qs] += __shfl_xor(l_s[qs], 32, 64);
    const float inv = 1.0f / l_s[qs];
    float ib[4];
#pragma unroll
    for (int r = 0; r < 4; ++r) ib[r] = __shfl(inv, quad * 4 + r, 64);
#pragma unroll
    for (int nt = 0; nt < 4; ++nt) {
#pragma unroll
      for (int r = 0; r < 4; ++r) {
        const int m = q0 + wave * 32 + qs * 16 + quad * 4 + r;
        ao[(size_t)(b * 1024 + m) * 768 + h * 64 + nt * 16 + l16] =
            f2bf(acc[qs][nt][r] * ib[r]);
      }
    }
  }
}

// ---------- out-proj GEMM + bias + residual -> x2 (f32), 128x64 tiles ----------
__global__ void gemm_outproj_kernel(const unsigned short* __restrict__ ao,
                                    const unsigned short* __restrict__ woutt,
                                    const float* __restrict__ b_out,
                                    const float* __restrict__ x,
                                    float* __restrict__ x2) {
  GEMM12864_PROLOGUE(12)
  gemm12864(ao, 768, woutt, 768, 768, row0, col0, As, Bs, acc);
#pragma unroll
  for (int mt = 0; mt < 2; ++mt)
#pragma unroll
    for (int nt = 0; nt < 4; ++nt) {
      const int j = col0 + nt * 16 + l16;
#pragma unroll
      for (int r = 0; r < 4; ++r) {
        const int m = row0 + wave * 32 + mt * 16 + quad * 4 + r;
        const size_t idx = (size_t)m * 768 + j;
        x2[idx] = acc[mt][nt][r] + b_out[j] + x[idx];
      }
    }
}

// ---------- MLP1: 128x128 tile single-buffer BK=64 + bias + GELU ----------
__global__ void gemm_mlp1_kernel(const unsigned short* __restrict__ h,
                                 const unsigned short* __restrict__ w1t,
                                 const float* __restrict__ b1,
                                 unsigned short* __restrict__ h1) {
  GEMM128_PROLOGUE(24)
  gemm128(h, 768, w1t, 768, 768, row0, col0, As, Bs, acc);
#pragma unroll
  for (int mt = 0; mt < 4; ++mt)
#pragma unroll
    for (int nt = 0; nt < 4; ++nt) {
      const int j = col0 + wc * 64 + nt * 16 + l16;
#pragma unroll
      for (int r = 0; r < 4; ++r) {
        const int m = row0 + wr * 64 + mt * 16 + quad * 4 + r;
        const float y = acc[mt][nt][r] + b1[j];
        h1[(size_t)m * 3072 + j] = f2bf(gelu_f(y));
      }
    }
}

// ---------- MLP2 GEMM + bias + residual -> out (f32), 128x64 tiles ----------
__global__ void gemm_mlp2_kernel(const unsigned short* __restrict__ h1,
                                 const unsigned short* __restrict__ w2t,
                                 const float* __restrict__ b2,
                                 const float* __restrict__ x2,
                                 float* __restrict__ out) {
  GEMM12864_PROLOGUE(12)
  gemm12864(h1, 3072, w2t, 3072, 3072, row0, col0, As, Bs, acc);
#pragma unroll
  for (int mt = 0; mt < 2; ++mt)
#pragma unroll
    for (int nt = 0; nt < 4; ++nt) {
      const int j = col0 + nt * 16 + l16;
#pragma unroll
      for (int r = 0; r < 4; ++r) {
        const int m = row0 + wave * 32 + mt * 16 + quad * 4 + r;
        const size_t idx = (size_t)m * 768 + j;
        out[idx] = acc[mt][nt][r] + b2[j] + x2[idx];
      }
    }
}

// ---------- launch ----------
extern "C" void kernel_launch(void* const* d_in, const int* in_sizes, int n_in,
                              void* d_out, int out_size, void* d_ws, size_t ws_size,
                              hipStream_t stream) {
  const float* x       = (const float*)d_in[0];
  const float* q_extra = (const float*)d_in[1];
  const float* ln1_g   = (const float*)d_in[2];
  const float* ln1_b   = (const float*)d_in[3];
  const float* w_kv    = (const float*)d_in[4];
  const float* w_out   = (const float*)d_in[5];
  const float* b_out   = (const float*)d_in[6];
  const float* ln2_g   = (const float*)d_in[7];
  const float* ln2_b   = (const float*)d_in[8];
  const float* w1      = (const float*)d_in[9];
  const float* b1      = (const float*)d_in[10];
  const float* w2      = (const float*)d_in[11];
  const float* b2      = (const float*)d_in[12];
  float* out = (float*)d_out;

  char* ws = (char*)d_ws;
  unsigned short* xn    = (unsigned short*)(ws);
  _Float16*       kbuf  = (_Float16*)(ws + 12582912);
  _Float16*       vtbuf = (_Float16*)(ws + 25165824);
  unsigned short* ao    = (unsigned short*)(ws + 37748736);
  float*          x2    = (float*)(ws + 50331648);
  unsigned short* h1    = (unsigned short*)(ws + 75497472);
  unsigned short* hbuf  = xn;   // xn dead after kv GEMM
  unsigned short* wkvt  = ao;                          // dead before attn writes ao
  unsigned short* woutt = h1;                          // dead before mlp1 writes h1
  unsigned short* w1t   = (unsigned short*)kbuf;       // kbuf dead after attn
  unsigned short* w2t   = (unsigned short*)vtbuf;      // vtbuf dead after attn

  // ln1 (2048) + w_kv trans (1152) + w_out trans (576) fused
  prep1_kernel<<<3776, 256, 0, stream>>>(x, ln1_g, ln1_b, xn,
                                         w_kv, wkvt, w_out, woutt);
  gemm_kv_kernel<<<1536, 256, 0, stream>>>(xn, wkvt, kbuf, vtbuf);
  attn_kernel<<<768, 256, 0, stream>>>(q_extra, kbuf, vtbuf, ao);
  // w1 (768x3072, 96x24 = 2304) + w2 (3072x768, 24x96 = 2304)
  wtrans2_kernel<<<4608, 256, 0, stream>>>(w1, w1t, 768, 3072, 96, 2304,
                                           w2, w2t, 3072, 768, 24);
  gemm_outproj_kernel<<<768, 256, 0, stream>>>(ao, woutt, b_out, x, x2);
  ln_kernel<<<2048, 256, 0, stream>>>(x2, ln2_g, ln2_b, hbuf);
  gemm_mlp1_kernel<<<1536, 256, 0, stream>>>(hbuf, w1t, b1, h1);
  gemm_mlp2_kernel<<<768, 256, 0, stream>>>(h1, w2t, b2, x2, out);
}

// Round 10
// 347.618 us; speedup vs baseline: 1.0445x; 1.0445x over previous
//
#include <hip/hip_runtime.h>
#include <math.h>

// ---------- types ----------
typedef __attribute__((ext_vector_type(8))) short short8;
typedef __attribute__((ext_vector_type(8))) _Float16 half8;
typedef __attribute__((ext_vector_type(2))) __fp16 fp16x2;
typedef __attribute__((ext_vector_type(4))) float float4v;
typedef __attribute__((ext_vector_type(4))) unsigned short ushort4v;

__device__ __forceinline__ unsigned short f2bf(float f) {
  union { unsigned int i; float f; } x; x.f = f;
  unsigned int r = x.i + 0x7fffu + ((x.i >> 16) & 1u);  // round-nearest-even
  return (unsigned short)(r >> 16);
}

// branch-free exact-GELU via Abramowitz-Stegun 7.1.26 (|erf err| <= 1.5e-7)
__device__ __forceinline__ float gelu_f(float y) {
  const float z = fabsf(y) * 0.70710678118654752f;
  const float t = 1.0f / (1.0f + 0.3275911f * z);
  const float poly = t * (0.254829592f + t * (-0.284496736f +
                     t * (1.421413741f + t * (-1.453152027f + t * 1.061405429f))));
  const float e = exp2f(-z * z * 1.44269504088896f);
  const float erfz = copysignf(1.0f - poly * e, y);
  return 0.5f * y * (1.0f + erfz);
}

// ---------- LayerNorm row body (one row per wave) ----------
__device__ __forceinline__ void ln_row(const float* __restrict__ in,
                                       const float* __restrict__ g,
                                       const float* __restrict__ b,
                                       unsigned short* __restrict__ out,
                                       int row, int lane) {
  const float* xr = in + (size_t)row * 768 + lane * 4;
  const float4 v0 = *(const float4*)(xr);
  const float4 v1 = *(const float4*)(xr + 256);
  const float4 v2 = *(const float4*)(xr + 512);
  float s  = (v0.x + v0.y) + (v0.z + v0.w) + (v1.x + v1.y) + (v1.z + v1.w)
           + (v2.x + v2.y) + (v2.z + v2.w);
  float s2 = v0.x*v0.x + v0.y*v0.y + v0.z*v0.z + v0.w*v0.w
           + v1.x*v1.x + v1.y*v1.y + v1.z*v1.z + v1.w*v1.w
           + v2.x*v2.x + v2.y*v2.y + v2.z*v2.z + v2.w*v2.w;
  for (int off = 32; off > 0; off >>= 1) {
    s  += __shfl_xor(s, off, 64);
    s2 += __shfl_xor(s2, off, 64);
  }
  const float mu = s * (1.0f / 768.0f);
  const float var = s2 * (1.0f / 768.0f) - mu * mu;
  const float rstd = rsqrtf(var + 1e-5f);
  const float* gp = g + lane * 4;
  const float* bp = b + lane * 4;
  unsigned short* orow = out + (size_t)row * 768 + lane * 4;
#pragma unroll
  for (int k = 0; k < 3; ++k) {
    const float4 v = (k == 0) ? v0 : (k == 1) ? v1 : v2;
    const float4 gv = *(const float4*)(gp + k * 256);
    const float4 bv = *(const float4*)(bp + k * 256);
    ushort4v o;
    o.x = f2bf((v.x - mu) * rstd * gv.x + bv.x);
    o.y = f2bf((v.y - mu) * rstd * gv.y + bv.y);
    o.z = f2bf((v.z - mu) * rstd * gv.z + bv.z);
    o.w = f2bf((v.w - mu) * rstd * gv.w + bv.w);
    *(ushort4v*)(orow + k * 256) = o;
  }
}

// ---------- LayerNorm kernel ----------
__global__ void ln_kernel(const float* __restrict__ in, const float* __restrict__ g,
                          const float* __restrict__ b, unsigned short* __restrict__ out) {
  ln_row(in, g, b, out, blockIdx.x * 4 + (threadIdx.x >> 6), threadIdx.x & 63);
}

// ---------- wtrans body: f32 (K,N) -> bf16 (N,K), one 32x32 tile ----------
__device__ __forceinline__ void wtrans_tile(const float* __restrict__ in,
                                            unsigned short* __restrict__ out,
                                            int K, int N, int bx, int by) {
  __shared__ float tile[32][33];
  const int k0 = by * 32, n0 = bx * 32;
  const int tr = threadIdx.x >> 5, tc = threadIdx.x & 31;
#pragma unroll
  for (int i = 0; i < 4; ++i)
    tile[tr + i * 8][tc] = in[(size_t)(k0 + tr + i * 8) * N + n0 + tc];
  __syncthreads();
#pragma unroll
  for (int i = 0; i < 4; ++i)
    out[(size_t)(n0 + tr + i * 8) * K + k0 + tc] = f2bf(tile[tc][tr + i * 8]);
}

// ---------- fused: ln1 (2048 blocks) + w_kv trans (1152) + w_out trans (576) ----------
__global__ void prep1_kernel(const float* __restrict__ x, const float* __restrict__ g,
                             const float* __restrict__ b, unsigned short* __restrict__ xn,
                             const float* __restrict__ wkv, unsigned short* __restrict__ wkvt,
                             const float* __restrict__ wout, unsigned short* __restrict__ woutt) {
  int id = (int)blockIdx.x;
  if (id < 2048) {
    ln_row(x, g, b, xn, id * 4 + (threadIdx.x >> 6), threadIdx.x & 63);
  } else if (id < 2048 + 1152) {
    id -= 2048;
    wtrans_tile(wkv, wkvt, 768, 1536, id % 48, id / 48);
  } else {
    id -= 2048 + 1152;
    wtrans_tile(wout, woutt, 768, 768, id % 24, id / 24);
  }
}

// ---------- fused pair of weight transposes (w1 + w2) ----------
__global__ void wtrans2_kernel(const float* __restrict__ inA, unsigned short* __restrict__ outA,
                               int KA, int NA, int bxA, int nA,
                               const float* __restrict__ inB, unsigned short* __restrict__ outB,
                               int KB, int NB, int bxB) {
  int id = (int)blockIdx.x;
  if (id < nA) wtrans_tile(inA, outA, KA, NA, id % bxA, id / bxA);
  else { id -= nA; wtrans_tile(inB, outB, KB, NB, id % bxB, id / bxB); }
}

// ---------- XCD-aware block swizzle ----------
#define SWIZ_BLOCK(GX, TW)                                        \
  const int _id = (int)blockIdx.x;                                \
  const int _gy8 = (int)gridDim.x / (8 * (GX));                   \
  const int _xcd = _id & 7, _jj = _id >> 3;                       \
  const int row0 = (_xcd * _gy8 + _jj / (GX)) * 128;              \
  const int col0 = (_jj % (GX)) * (TW);

#define ASM_FENCE asm volatile("" ::: "memory")

// ---------- GEMM core 128x128, BK=64, XOR-swizzled LDS (single-buffer) ----------
__device__ __forceinline__ void gemm128(
    const unsigned short* __restrict__ A, int lda,
    const unsigned short* __restrict__ Bt, int ldb, int K,
    int row0, int col0,
    unsigned short* As, unsigned short* Bs,
    float4v acc[4][4]) {
  const int t = threadIdx.x, lane = t & 63, wave = t >> 6;
  const int quad = lane >> 4, l16 = lane & 15;
  const int wr = wave >> 1, wc = wave & 1;
  const int srow = lane >> 3;
  const int scol = ((lane & 7) ^ srow) * 8;
#pragma unroll
  for (int mt = 0; mt < 4; ++mt)
#pragma unroll
    for (int nt = 0; nt < 4; ++nt) acc[mt][nt] = (float4v)(0.0f);

  for (int kk = 0; kk < K; kk += 64) {
    __syncthreads();
#pragma unroll
    for (int j = 0; j < 4; ++j) {
      const int chunk = wave * 4 + j;
      const int r = chunk * 8 + srow;
      __builtin_amdgcn_global_load_lds(
          (const __attribute__((address_space(1))) unsigned int*)(A + (size_t)(row0 + r) * lda + kk + scol),
          (__attribute__((address_space(3))) unsigned int*)(As + chunk * 512),
          16, 0, 0);
      __builtin_amdgcn_global_load_lds(
          (const __attribute__((address_space(1))) unsigned int*)(Bt + (size_t)(col0 + r) * ldb + kk + scol),
          (__attribute__((address_space(3))) unsigned int*)(Bs + chunk * 512),
          16, 0, 0);
    }
    __syncthreads();
#pragma unroll
    for (int ks = 0; ks < 2; ++ks) {
      const int gsw = ((ks * 4 + quad) ^ (l16 & 7)) * 8;
      short8 af[4], bfv[4];
#pragma unroll
      for (int i = 0; i < 4; ++i) {
        af[i]  = *(const short8*)(As + (wr * 64 + i * 16 + l16) * 64 + gsw);
        bfv[i] = *(const short8*)(Bs + (wc * 64 + i * 16 + l16) * 64 + gsw);
      }
#pragma unroll
      for (int mt = 0; mt < 4; ++mt)
#pragma unroll
        for (int nt = 0; nt < 4; ++nt)
          acc[mt][nt] = __builtin_amdgcn_mfma_f32_16x16x32_bf16(af[mt], bfv[nt], acc[mt][nt], 0, 0, 0);
    }
  }
}

#define GEMM128_PROLOGUE(GX)                                     \
  __shared__ unsigned short As[128 * 64];                        \
  __shared__ unsigned short Bs[128 * 64];                        \
  float4v acc[4][4];                                             \
  SWIZ_BLOCK(GX, 128)                                            \
  const int t = threadIdx.x, lane = t & 63, wave = t >> 6;       \
  const int quad = lane >> 4, l16 = lane & 15;                   \
  const int wr = wave >> 1, wc = wave & 1; (void)t;

// ---------- GEMM core 128x64, BK=64, counted-vmcnt double-buffer ----------
__device__ __forceinline__ void stage12864(
    const unsigned short* __restrict__ A, int lda,
    const unsigned short* __restrict__ Bt, int ldb,
    int row0, int col0, int kk,
    unsigned short* Asb, unsigned short* Bsb,
    int wave, int srow, int scol) {
#pragma unroll
  for (int j = 0; j < 4; ++j) {
    const int chunk = wave * 4 + j;
    const int r = chunk * 8 + srow;
    __builtin_amdgcn_global_load_lds(
        (const __attribute__((address_space(1))) unsigned int*)(A + (size_t)(row0 + r) * lda + kk + scol),
        (__attribute__((address_space(3))) unsigned int*)(Asb + chunk * 512),
        16, 0, 0);
  }
#pragma unroll
  for (int j = 0; j < 2; ++j) {
    const int chunk = wave * 2 + j;
    const int r = chunk * 8 + srow;
    __builtin_amdgcn_global_load_lds(
        (const __attribute__((address_space(1))) unsigned int*)(Bt + (size_t)(col0 + r) * ldb + kk + scol),
        (__attribute__((address_space(3))) unsigned int*)(Bsb + chunk * 512),
        16, 0, 0);
  }
}

__device__ __forceinline__ void mfma_step12864(
    const unsigned short* Ab, const unsigned short* Bb,
    int wave, int quad, int l16, float4v acc[2][4]) {
#pragma unroll
  for (int ks = 0; ks < 2; ++ks) {
    const int gsw = ((ks * 4 + quad) ^ (l16 & 7)) * 8;
    short8 af[2], bfv[4];
#pragma unroll
    for (int i = 0; i < 2; ++i)
      af[i] = *(const short8*)(Ab + (wave * 32 + i * 16 + l16) * 64 + gsw);
#pragma unroll
    for (int i = 0; i < 4; ++i)
      bfv[i] = *(const short8*)(Bb + (i * 16 + l16) * 64 + gsw);
#pragma unroll
    for (int mt = 0; mt < 2; ++mt)
#pragma unroll
      for (int nt = 0; nt < 4; ++nt)
        acc[mt][nt] = __builtin_amdgcn_mfma_f32_16x16x32_bf16(af[mt], bfv[nt], acc[mt][nt], 0, 0, 0);
  }
}

// K must be a multiple of 128 and >= 256.
__device__ __forceinline__ void gemm12864(
    const unsigned short* __restrict__ A, int lda,
    const unsigned short* __restrict__ Bt, int ldb, int K,
    int row0, int col0,
    unsigned short* As, unsigned short* Bs,
    float4v acc[2][4]) {
  const int t = threadIdx.x, lane = t & 63, wave = t >> 6;
  const int quad = lane >> 4, l16 = lane & 15;
  const int srow = lane >> 3;
  const int scol = ((lane & 7) ^ srow) * 8;
#pragma unroll
  for (int mt = 0; mt < 2; ++mt)
#pragma unroll
    for (int nt = 0; nt < 4; ++nt) acc[mt][nt] = (float4v)(0.0f);

  stage12864(A, lda, Bt, ldb, row0, col0, 0, As, Bs, wave, srow, scol);
  stage12864(A, lda, Bt, ldb, row0, col0, 64, As + 8192, Bs + 4096, wave, srow, scol);

  for (int kk = 0; kk < K - 128; kk += 128) {
    asm volatile("s_waitcnt vmcnt(6)" ::: "memory");
    __builtin_amdgcn_s_barrier();
    ASM_FENCE;
    mfma_step12864(As, Bs, wave, quad, l16, acc);
    ASM_FENCE;
    __builtin_amdgcn_s_barrier();
    ASM_FENCE;
    stage12864(A, lda, Bt, ldb, row0, col0, kk + 128, As, Bs, wave, srow, scol);

    asm volatile("s_waitcnt vmcnt(6)" ::: "memory");
    __builtin_amdgcn_s_barrier();
    ASM_FENCE;
    mfma_step12864(As + 8192, Bs + 4096, wave, quad, l16, acc);
    ASM_FENCE;
    __builtin_amdgcn_s_barrier();
    ASM_FENCE;
    stage12864(A, lda, Bt, ldb, row0, col0, kk + 192, As + 8192, Bs + 4096, wave, srow, scol);
  }
  asm volatile("s_waitcnt vmcnt(6)" ::: "memory");
  __builtin_amdgcn_s_barrier();
  ASM_FENCE;
  mfma_step12864(As, Bs, wave, quad, l16, acc);
  asm volatile("s_waitcnt vmcnt(0)" ::: "memory");
  __builtin_amdgcn_s_barrier();
  ASM_FENCE;
  mfma_step12864(As + 8192, Bs + 4096, wave, quad, l16, acc);
}

#define GEMM12864_PROLOGUE(GX)                                   \
  __shared__ unsigned short As[2 * 128 * 64];                    \
  __shared__ unsigned short Bs[2 * 64 * 64];                     \
  float4v acc[2][4];                                             \
  SWIZ_BLOCK(GX, 64)                                             \
  const int t = threadIdx.x, lane = t & 63, wave = t >> 6;       \
  const int quad = lane >> 4, l16 = lane & 15; (void)t;

// ---------- kv GEMM: xn @ w_kv -> k (B,H,N,DH) f16, v^T (B,H,DH,N) f16 ----------
__global__ void gemm_kv_kernel(const unsigned short* __restrict__ xn,
                               const unsigned short* __restrict__ wkvt,
                               _Float16* __restrict__ kbuf,
                               _Float16* __restrict__ vtbuf) {
  GEMM12864_PROLOGUE(24)
  gemm12864(xn, 768, wkvt, 768, 768, row0, col0, As, Bs, acc);
#pragma unroll
  for (int mt = 0; mt < 2; ++mt)
#pragma unroll
    for (int nt = 0; nt < 4; ++nt) {
      const int j = col0 + nt * 16 + l16;
#pragma unroll
      for (int r = 0; r < 4; ++r) {
        const int m = row0 + wave * 32 + mt * 16 + quad * 4 + r;
        const int bb = m >> 10, n = m & 1023;
        const float c = acc[mt][nt][r];
        if (j < 768) {
          const int hh = j >> 6, d = j & 63;
          kbuf[((size_t)(bb * 12 + hh) * 1024 + n) * 64 + d] = (_Float16)c;
        } else {
          const int j2 = j - 768, hh = j2 >> 6, d = j2 & 63;
          vtbuf[((size_t)(bb * 12 + hh) * 64 + d) * 1024 + n] = (_Float16)c;
        }
      }
    }
}

// ---------- MFMA flash attention, f16 ----------
// Round-10: 8 waves x 16 q-rows (512 threads), grid 768 = 3 blocks/CU.
// 24 waves/CU (vs 12): wave-level TLP hides each wave's serial softmax chain
// under other waves' MFMA clusters (MFMA/VALU pipes overlap across waves).
// LDS unchanged (36.9 KB -> cap 4 >= 3). Per-row math order identical to the
// 4-wave version -> bit-identical output.
#define AST 72
#define PST 72
__global__ __launch_bounds__(512, 3)
void attn_kernel(const float* __restrict__ q_extra,
                 const _Float16* __restrict__ kbuf,
                 const _Float16* __restrict__ vtbuf,
                 unsigned short* __restrict__ ao) {
  __shared__ _Float16 Ks[64 * AST];
  __shared__ _Float16 Vs[64 * AST];
  __shared__ _Float16 Ps[8][16 * PST];
  const int id = (int)blockIdx.x;
  const int pair = id % 96, qb = id / 96;
  const int h = pair >> 3, b = pair & 7;
  const int q0 = qb * 128;
  const int t = threadIdx.x, lane = t & 63, wave = t >> 6;
  const int quad = lane >> 4, l16 = lane & 15;

  // Q fragment (B-operand layout) f16, pre-scaled by 0.125*log2(e)
  const float QS = 0.125f * 1.44269504088896f;
  half8 qf0, qf1;
  {
    const float* qp = q_extra +
        ((size_t)((b * 1024 + q0 + wave * 16 + l16) * 12 + h)) * 64 + quad * 8;
    float4 a0 = *(const float4*)(qp);
    float4 a1 = *(const float4*)(qp + 4);
    float4 c0 = *(const float4*)(qp + 32);
    float4 c1 = *(const float4*)(qp + 36);
    union { fp16x2 h2[4]; half8 h8; } u0, u1;
    u0.h2[0] = __builtin_amdgcn_cvt_pkrtz(a0.x * QS, a0.y * QS);
    u0.h2[1] = __builtin_amdgcn_cvt_pkrtz(a0.z * QS, a0.w * QS);
    u0.h2[2] = __builtin_amdgcn_cvt_pkrtz(a1.x * QS, a1.y * QS);
    u0.h2[3] = __builtin_amdgcn_cvt_pkrtz(a1.z * QS, a1.w * QS);
    u1.h2[0] = __builtin_amdgcn_cvt_pkrtz(c0.x * QS, c0.y * QS);
    u1.h2[1] = __builtin_amdgcn_cvt_pkrtz(c0.z * QS, c0.w * QS);
    u1.h2[2] = __builtin_amdgcn_cvt_pkrtz(c1.x * QS, c1.y * QS);
    u1.h2[3] = __builtin_amdgcn_cvt_pkrtz(c1.z * QS, c1.w * QS);
    qf0 = u0.h8; qf1 = u1.h8;
  }

  const _Float16* kb = kbuf + (size_t)(b * 12 + h) * 65536;
  const _Float16* vb = vtbuf + (size_t)(b * 12 + h) * 65536;
  // staging: 512 threads x 16 B = one 64x64 f16 chunk
  const int srow = t >> 3, su = (t & 7) * 8;

  // prefetch chunk 0
  half8 kp = *(const half8*)(kb + (size_t)srow * 64 + su);
  half8 vp = *(const half8*)(vb + (size_t)srow * 1024 + su);

  float m_s = -1e30f, l_s = 0.0f;
  float4v acc[4];
#pragma unroll
  for (int nt = 0; nt < 4; ++nt) acc[nt] = (float4v)(0.0f);
  _Float16* pw = Ps[wave];

  for (int c = 0; c < 16; ++c) {
    __syncthreads();
    *(half8*)(Ks + srow * AST + su) = kp;
    *(half8*)(Vs + srow * AST + su) = vp;
    if (c < 15) {
      const int key1 = (c + 1) * 64;
      kp = *(const half8*)(kb + (size_t)(key1 + srow) * 64 + su);
      vp = *(const half8*)(vb + (size_t)srow * 1024 + key1 + su);
    }
    __syncthreads();

    // S^T = K @ Q^T (log2-domain scores)
    float4v s[4];
    __builtin_amdgcn_s_setprio(1);
#pragma unroll
    for (int kt = 0; kt < 4; ++kt) {
      const _Float16* kr = Ks + (kt * 16 + l16) * AST;
      half8 kf0 = *(const half8*)(kr + quad * 8);
      half8 kf1 = *(const half8*)(kr + 32 + quad * 8);
      float4v a = (float4v)(0.f);
      a = __builtin_amdgcn_mfma_f32_16x16x32_f16(kf0, qf0, a, 0, 0, 0);
      a = __builtin_amdgcn_mfma_f32_16x16x32_f16(kf1, qf1, a, 0, 0, 0);
      s[kt] = a;
    }
    __builtin_amdgcn_s_setprio(0);

    // per-lane max over own 16 scores (v_max3 triples)
    const float t1 = fmaxf(fmaxf(s[0][0], s[0][1]), s[0][2]);
    const float t2 = fmaxf(fmaxf(s[0][3], s[1][0]), s[1][1]);
    const float t3 = fmaxf(fmaxf(s[1][2], s[1][3]), s[2][0]);
    const float t4 = fmaxf(fmaxf(s[2][1], s[2][2]), s[2][3]);
    const float t5 = fmaxf(fmaxf(s[3][0], s[3][1]), s[3][2]);
    const float mx = fmaxf(fmaxf(fmaxf(t1, t2), t3),
                           fmaxf(fmaxf(t4, t5), s[3][3]));

    // defer-rescale: cheap wave-collective check, no cross-lane reduce
    if (__any(mx > m_s + 8.0f)) {
      float gm = fmaxf(mx, __shfl_xor(mx, 16, 64));
      gm = fmaxf(gm, __shfl_xor(gm, 32, 64));
      const float mn = fmaxf(m_s, gm);
      const float alpha = exp2f(m_s - mn);
      m_s = mn;
      l_s *= alpha;
      float ab[4];
#pragma unroll
      for (int r = 0; r < 4; ++r) ab[r] = __shfl(alpha, quad * 4 + r, 64);
#pragma unroll
      for (int nt = 0; nt < 4; ++nt)
#pragma unroll
        for (int r = 0; r < 4; ++r) acc[nt][r] *= ab[r];
    }

    float sum = 0.0f;
#pragma unroll
    for (int kt = 0; kt < 4; ++kt) {
      const float p0 = exp2f(s[kt][0] - m_s);
      const float p1 = exp2f(s[kt][1] - m_s);
      const float p2 = exp2f(s[kt][2] - m_s);
      const float p3 = exp2f(s[kt][3] - m_s);
      sum += (p0 + p1) + (p2 + p3);
      union { fp16x2 h2[2]; uint2 u; } pk;
      pk.h2[0] = __builtin_amdgcn_cvt_pkrtz(p0, p1);
      pk.h2[1] = __builtin_amdgcn_cvt_pkrtz(p2, p3);
      *(uint2*)(pw + l16 * PST + kt * 16 + quad * 4) = pk.u;
    }
    l_s += sum;   // per-lane partial; cross-quad reduce deferred to end

    // O += P @ V
    half8 pf0 = *(const half8*)(pw + l16 * PST + quad * 8);
    half8 pf1 = *(const half8*)(pw + l16 * PST + 32 + quad * 8);
    __builtin_amdgcn_s_setprio(1);
#pragma unroll
    for (int nt = 0; nt < 4; ++nt) {
      const _Float16* vr = Vs + (nt * 16 + l16) * AST;
      half8 vf0 = *(const half8*)(vr + quad * 8);
      half8 vf1 = *(const half8*)(vr + 32 + quad * 8);
      acc[nt] = __builtin_amdgcn_mfma_f32_16x16x32_f16(pf0, vf0, acc[nt], 0, 0, 0);
      acc[nt] = __builtin_amdgcn_mfma_f32_16x16x32_f16(pf1, vf1, acc[nt], 0, 0, 0);
    }
    __builtin_amdgcn_s_setprio(0);
  }

  // cross-quad l_s reduction (once)
  l_s += __shfl_xor(l_s, 16, 64);
  l_s += __shfl_xor(l_s, 32, 64);
  const float inv = 1.0f / l_s;
  float ib[4];
#pragma unroll
  for (int r = 0; r < 4; ++r) ib[r] = __shfl(inv, quad * 4 + r, 64);
#pragma unroll
  for (int nt = 0; nt < 4; ++nt) {
#pragma unroll
    for (int r = 0; r < 4; ++r) {
      const int m = q0 + wave * 16 + quad * 4 + r;
      ao[(size_t)(b * 1024 + m) * 768 + h * 64 + nt * 16 + l16] =
          f2bf(acc[nt][r] * ib[r]);
    }
  }
}

// ---------- out-proj GEMM + bias + residual -> x2 (f32), 128x64 tiles ----------
__global__ void gemm_outproj_kernel(const unsigned short* __restrict__ ao,
                                    const unsigned short* __restrict__ woutt,
                                    const float* __restrict__ b_out,
                                    const float* __restrict__ x,
                                    float* __restrict__ x2) {
  GEMM12864_PROLOGUE(12)
  gemm12864(ao, 768, woutt, 768, 768, row0, col0, As, Bs, acc);
#pragma unroll
  for (int mt = 0; mt < 2; ++mt)
#pragma unroll
    for (int nt = 0; nt < 4; ++nt) {
      const int j = col0 + nt * 16 + l16;
#pragma unroll
      for (int r = 0; r < 4; ++r) {
        const int m = row0 + wave * 32 + mt * 16 + quad * 4 + r;
        const size_t idx = (size_t)m * 768 + j;
        x2[idx] = acc[mt][nt][r] + b_out[j] + x[idx];
      }
    }
}

// ---------- MLP1: 128x128 tile single-buffer BK=64 + bias + GELU ----------
__global__ void gemm_mlp1_kernel(const unsigned short* __restrict__ h,
                                 const unsigned short* __restrict__ w1t,
                                 const float* __restrict__ b1,
                                 unsigned short* __restrict__ h1) {
  GEMM128_PROLOGUE(24)
  gemm128(h, 768, w1t, 768, 768, row0, col0, As, Bs, acc);
#pragma unroll
  for (int mt = 0; mt < 4; ++mt)
#pragma unroll
    for (int nt = 0; nt < 4; ++nt) {
      const int j = col0 + wc * 64 + nt * 16 + l16;
#pragma unroll
      for (int r = 0; r < 4; ++r) {
        const int m = row0 + wr * 64 + mt * 16 + quad * 4 + r;
        const float y = acc[mt][nt][r] + b1[j];
        h1[(size_t)m * 3072 + j] = f2bf(gelu_f(y));
      }
    }
}

// ---------- MLP2 GEMM + bias + residual -> out (f32), 128x64 tiles ----------
__global__ void gemm_mlp2_kernel(const unsigned short* __restrict__ h1,
                                 const unsigned short* __restrict__ w2t,
                                 const float* __restrict__ b2,
                                 const float* __restrict__ x2,
                                 float* __restrict__ out) {
  GEMM12864_PROLOGUE(12)
  gemm12864(h1, 3072, w2t, 3072, 3072, row0, col0, As, Bs, acc);
#pragma unroll
  for (int mt = 0; mt < 2; ++mt)
#pragma unroll
    for (int nt = 0; nt < 4; ++nt) {
      const int j = col0 + nt * 16 + l16;
#pragma unroll
      for (int r = 0; r < 4; ++r) {
        const int m = row0 + wave * 32 + mt * 16 + quad * 4 + r;
        const size_t idx = (size_t)m * 768 + j;
        out[idx] = acc[mt][nt][r] + b2[j] + x2[idx];
      }
    }
}

// ---------- launch ----------
extern "C" void kernel_launch(void* const* d_in, const int* in_sizes, int n_in,
                              void* d_out, int out_size, void* d_ws, size_t ws_size,
                              hipStream_t stream) {
  const float* x       = (const float*)d_in[0];
  const float* q_extra = (const float*)d_in[1];
  const float* ln1_g   = (const float*)d_in[2];
  const float* ln1_b   = (const float*)d_in[3];
  const float* w_kv    = (const float*)d_in[4];
  const float* w_out   = (const float*)d_in[5];
  const float* b_out   = (const float*)d_in[6];
  const float* ln2_g   = (const float*)d_in[7];
  const float* ln2_b   = (const float*)d_in[8];
  const float* w1      = (const float*)d_in[9];
  const float* b1      = (const float*)d_in[10];
  const float* w2      = (const float*)d_in[11];
  const float* b2      = (const float*)d_in[12];
  float* out = (float*)d_out;

  char* ws = (char*)d_ws;
  unsigned short* xn    = (unsigned short*)(ws);
  _Float16*       kbuf  = (_Float16*)(ws + 12582912);
  _Float16*       vtbuf = (_Float16*)(ws + 25165824);
  unsigned short* ao    = (unsigned short*)(ws + 37748736);
  float*          x2    = (float*)(ws + 50331648);
  unsigned short* h1    = (unsigned short*)(ws + 75497472);
  unsigned short* hbuf  = xn;   // xn dead after kv GEMM
  unsigned short* wkvt  = ao;                          // dead before attn writes ao
  unsigned short* woutt = h1;                          // dead before mlp1 writes h1
  unsigned short* w1t   = (unsigned short*)kbuf;       // kbuf dead after attn
  unsigned short* w2t   = (unsigned short*)vtbuf;      // vtbuf dead after attn

  // ln1 (2048) + w_kv trans (1152) + w_out trans (576) fused
  prep1_kernel<<<3776, 256, 0, stream>>>(x, ln1_g, ln1_b, xn,
                                         w_kv, wkvt, w_out, woutt);
  gemm_kv_kernel<<<1536, 256, 0, stream>>>(xn, wkvt, kbuf, vtbuf);
  attn_kernel<<<768, 512, 0, stream>>>(q_extra, kbuf, vtbuf, ao);
  // w1 (768x3072, 96x24 = 2304) + w2 (3072x768, 24x96 = 2304)
  wtrans2_kernel<<<4608, 256, 0, stream>>>(w1, w1t, 768, 3072, 96, 2304,
                                           w2, w2t, 3072, 768, 24);
  gemm_outproj_kernel<<<768, 256, 0, stream>>>(ao, woutt, b_out, x, x2);
  ln_kernel<<<2048, 256, 0, stream>>>(x2, ln2_g, ln2_b, hbuf);
  gemm_mlp1_kernel<<<1536, 256, 0, stream>>>(hbuf, w1t, b1, h1);
  gemm_mlp2_kernel<<<768, 256, 0, stream>>>(h1, w2t, b2, x2, out);
}